// Round 12
// baseline (144.765 us; speedup 1.0000x reference)
//
#include <hip/hip_runtime.h>
#include <hip/hip_bf16.h>
#include <cstdint>

// Problem dims (fixed by reference setup_inputs)
constexpr int Bn = 16;    // batch
constexpr int Sn = 1024;  // source length
constexpr int Tn = 512;   // query steps
constexpr int QD = 256;   // query vec size
constexpr int En = 512;   // src encoding size
constexpr int Hn = 4;     // heads
constexpr float SLOPE = 0.01f;   // jax.nn.leaky_relu default
constexpr float NEG_INF = -1e9f;
constexpr int Mn = Bn * Sn;      // 16384 rows of the projection GEMM

typedef _Float16 f16;
typedef f16 f16x4 __attribute__((ext_vector_type(4)));
typedef f16 f16x8 __attribute__((ext_vector_type(8)));
typedef float f32x4 __attribute__((ext_vector_type(4)));

// async global->LDS, 16B per lane; dest = wave-uniform base + lane*16
#define G2L(g, l) __builtin_amdgcn_global_load_lds(                      \
    (const __attribute__((address_space(1))) void*)(g),                  \
    (__attribute__((address_space(3))) void*)(l), 16, 0, 0)

#define VM4 asm volatile("s_waitcnt vmcnt(4)" ::: "memory")
#define VM0 asm volatile("s_waitcnt vmcnt(0)" ::: "memory")
#define LG0 asm volatile("s_waitcnt lgkmcnt(0)" ::: "memory")

// ---------------------------------------------------------------------------
// K0: detect mask dtype (bool bytes vs int32) — writes flag (1 = int32) to ws
// ---------------------------------------------------------------------------
__global__ void detect_mask_kernel(const unsigned char* __restrict__ mask_bytes,
                                   int* __restrict__ flag) {
    __shared__ int cnt;
    if (threadIdx.x == 0) cnt = 0;
    __syncthreads();
    int local = 0;
    for (int p = threadIdx.x; p < 4096; p += 256) {
        if ((p & 3) != 0 && mask_bytes[p] != 0) local++;
    }
    atomicAdd(&cnt, local);
    __syncthreads();
    if (threadIdx.x == 0) flag[0] = (cnt == 0) ? 1 : 0;
}

// ---------------------------------------------------------------------------
// C1: split src (16384x512 f32) into Ah + Al (f16 row-major), exact hi/lo
// ---------------------------------------------------------------------------
__global__ __launch_bounds__(256) void conv_a_kernel(
    const float* __restrict__ src, f16* __restrict__ Ah, f16* __restrict__ Al)
{
    const size_t i4 = (size_t)blockIdx.x * 256 + threadIdx.x;
    const size_t base = i4 * 4;
    const float4 v = *(const float4*)(src + base);
    f16x4 hi, lo;
    const float xs[4] = {v.x, v.y, v.z, v.w};
    #pragma unroll
    for (int j = 0; j < 4; ++j) {
        f16 h = (f16)xs[j];
        hi[j] = h;
        lo[j] = (f16)(xs[j] - (float)h);
    }
    *(f16x4*)(Ah + base) = hi;
    *(f16x4*)(Al + base) = lo;
}

// ---------------------------------------------------------------------------
// C2: W (512x1024 f32) -> Bht, Blt (1024x512 f16) transposed + hi/lo split
// ---------------------------------------------------------------------------
__global__ __launch_bounds__(256) void conv_b_kernel(
    const float* __restrict__ W, f16* __restrict__ Bht, f16* __restrict__ Blt)
{
    __shared__ float T[64][65];
    const int tid = threadIdx.x;
    const int n0 = blockIdx.x * 64;
    const int k0 = blockIdx.y * 64;
    #pragma unroll
    for (int p = 0; p < 4; ++p) {
        const int e = p * 256 + tid;
        const int r = e >> 4;
        const int c4 = e & 15;
        const float4 v = *(const float4*)(W + (size_t)(k0 + r) * (Hn * QD) + n0 + c4 * 4);
        T[r][c4 * 4 + 0] = v.x; T[r][c4 * 4 + 1] = v.y;
        T[r][c4 * 4 + 2] = v.z; T[r][c4 * 4 + 3] = v.w;
    }
    __syncthreads();
    #pragma unroll
    for (int p = 0; p < 4; ++p) {
        const int e = p * 256 + tid;
        const int r = e >> 4;
        const int c4 = e & 15;
        f16x4 hi, lo;
        #pragma unroll
        for (int j = 0; j < 4; ++j) {
            const float x = T[c4 * 4 + j][r];
            f16 h = (f16)x;
            hi[j] = h;
            lo[j] = (f16)(x - (float)h);
        }
        const size_t off = (size_t)(n0 + r) * En + k0 + c4 * 4;
        *(f16x4*)(Bht + off) = hi;
        *(f16x4*)(Blt + off) = lo;
    }
}

// ---------------------------------------------------------------------------
// C3: split query (512,16,256) f32 -> Qh, Ql (b,t,q) f16.
// ---------------------------------------------------------------------------
__global__ __launch_bounds__(256) void conv_q_kernel(
    const float* __restrict__ query, f16* __restrict__ Qh, f16* __restrict__ Ql)
{
    const int tid = threadIdx.x;
    const int rloc = tid >> 6;
    const int lane = tid & 63;
    const int row = blockIdx.x * 4 + rloc;   // (t,b) pair, t-major
    const int t = row >> 4, b = row & 15;
    const float4 v = *(const float4*)(query + (size_t)row * QD + lane * 4);
    f16x4 hi, lo;
    const float xs[4] = {v.x, v.y, v.z, v.w};
    #pragma unroll
    for (int j = 0; j < 4; ++j) {
        f16 h = (f16)xs[j];
        hi[j] = h;
        lo[j] = (f16)(xs[j] - (float)h);
    }
    const size_t off = ((size_t)(b * Tn + t)) * QD + lane * 4;
    *(f16x4*)(Qh + off) = hi;
    *(f16x4*)(Ql + off) = lo;
}

// ---------------------------------------------------------------------------
// K1: m201-style 256x256 tile, BK=32, ring-3, 8 waves (2M x 4N).
//   Per-wave output 128x64 = acc[8][4]. 48 K-tiles (3 split-phases x 16).
//   Each K-tile = 2 sub-phases (mh=0/1): {4x ds_read A (+4x B in ph0, regs
//   reused in ph1); stage 2 G2L; barrier; lgkm0; setprio; 16 MFMA; barrier}.
//   Ring-3 LDS 96 KB: stage target slot (t+2)%3 was last read at tile t-1
//   (barrier-proven WAR safety). Counted vmcnt: VM4 steady, VM0 tail.
//   Column packing c = [qhi(4)][head(4)][qlo(16)]: frag nf <-> head nf,
//   q = q0 + wn*16 + (l&15) -> head-combine is lane-local.
//   XOR chunk scheme (R6-validated): slot k4 = global k4 ^ ((row>>1)&3).
// ---------------------------------------------------------------------------
__global__ __launch_bounds__(512, 2) void gemm1_kernel(
    const f16* __restrict__ Ah, const f16* __restrict__ Al,
    const f16* __restrict__ Bht, const f16* __restrict__ Blt,
    const float* __restrict__ wcomb,
    f16* __restrict__ Ch, f16* __restrict__ Cl)
{
    __shared__ f16 lds_f[49152];   // 3 slots x 16384 f16 (A 8192 | B 8192) = 96 KB

    const int tid = threadIdx.x;
    const int l  = tid & 63;
    const int wv = tid >> 6;       // 0..7
    const int wm = wv >> 2;        // 0..1 (M half: 128 rows)
    const int wn = wv & 3;         // 0..3 (64-col group)
    const int m0 = blockIdx.x * 256;
    const int q0 = blockIdx.y * 64;

    // ---- staging constants: 1 G2L per half-tile per thread (8 KB ht) ----
    // chunk cc = wv*64 + l; row_local = wv*16 + (l>>2); k4 = l&3
    const int rls = wv * 16 + (l >> 2);                 // 0..127
    const int xk  = ((l & 3) ^ ((l >> 3) & 3)) * 8;     // source k-chunk (xor'd)
    const size_t stgA0 = (size_t)(m0 + rls) * En + xk;         // A half 0
    const size_t stgA1 = stgA0 + (size_t)128 * En;             // A half 1
    int rBv[2];
    #pragma unroll
    for (int h = 0; h < 2; ++h) {
        const int c = h * 128 + rls;   // tile col
        rBv[h] = ((c >> 4) & 3) * QD + q0 + ((c >> 6) * 16) + (c & 15);
    }
    const size_t stgB0 = (size_t)rBv[0] * En + xk;
    const size_t stgB1 = (size_t)rBv[1] * En + xk;

    // ---- fragment read constants (f16 offsets within a 16384-f16 slot) ----
    const int kx   = (((l >> 4) ^ ((l >> 1) & 3))) * 8;  // slot k-chunk
    const int aRow = (wm * 128 + (l & 15)) * 32 + kx;    // + mh*2048 + mf*512
    const int bCol = 8192 + (wn * 64 + (l & 15)) * 32 + kx;  // + nf*512

    f32x4 acc[8][4];
    #pragma unroll
    for (int m = 0; m < 8; ++m)
        #pragma unroll
        for (int n = 0; n < 4; ++n) acc[m][n] = (f32x4){0.f, 0.f, 0.f, 0.f};

    auto stageAB = [&](int t, int pair) {   // pair 0 = A halves, 1 = B halves
        const int kbase = (t & 15) * 32;
        f16* dst = lds_f + (t % 3) * 16384 + pair * 8192 + wv * 512;
        if (pair == 0) {
            const f16* A = (t < 16) ? Ah : ((t < 32) ? Al : Ah);
            G2L(A + stgA0 + kbase, dst);
            G2L(A + stgA1 + kbase, dst + 4096);
        } else {
            const f16* B = (t < 32) ? Bht : Blt;
            G2L(B + stgB0 + kbase, dst);
            G2L(B + stgB1 + kbase, dst + 4096);
        }
    };

    // prologue: tiles 0,1 fully staged; VM4 -> tile 0 landed
    stageAB(0, 0); stageAB(0, 1);
    stageAB(1, 0); stageAB(1, 1);
    VM4;
    __builtin_amdgcn_s_barrier();

    #pragma unroll 3
    for (int t = 0; t < 48; ++t) {
        const f16* Lb = lds_f + (t % 3) * 16384;
        f16x8 bf[4], af0[4], af1[4];

        // ---- sub-phase 0 (mh = 0): read A-half(wm) quadrant 0 + all B ----
        #pragma unroll
        for (int mf = 0; mf < 4; ++mf)
            af0[mf] = *(const f16x8*)(Lb + aRow + mf * 512);
        #pragma unroll
        for (int nf = 0; nf < 4; ++nf)
            bf[nf] = *(const f16x8*)(Lb + bCol + nf * 512);
        if (t + 2 < 48) stageAB(t + 2, 0);
        __builtin_amdgcn_s_barrier();
        LG0;
        __builtin_amdgcn_sched_barrier(0);
        __builtin_amdgcn_s_setprio(1);
        #pragma unroll
        for (int mf = 0; mf < 4; ++mf) {
            #pragma unroll
            for (int nf = 0; nf < 4; ++nf)
                acc[mf][nf] = __builtin_amdgcn_mfma_f32_16x16x32_f16(
                    af0[mf], bf[nf], acc[mf][nf], 0, 0, 0);
        }
        __builtin_amdgcn_s_setprio(0);
        __builtin_amdgcn_s_barrier();

        // ---- sub-phase 1 (mh = 1): read A quadrant 1; B reused in regs ----
        #pragma unroll
        for (int mf = 0; mf < 4; ++mf)
            af1[mf] = *(const f16x8*)(Lb + aRow + 2048 + mf * 512);
        if (t + 2 < 48) stageAB(t + 2, 1);
        __builtin_amdgcn_s_barrier();
        LG0;
        __builtin_amdgcn_sched_barrier(0);
        __builtin_amdgcn_s_setprio(1);
        #pragma unroll
        for (int mf = 0; mf < 4; ++mf) {
            #pragma unroll
            for (int nf = 0; nf < 4; ++nf)
                acc[4 + mf][nf] = __builtin_amdgcn_mfma_f32_16x16x32_f16(
                    af1[mf], bf[nf], acc[4 + mf][nf], 0, 0, 0);
        }
        __builtin_amdgcn_s_setprio(0);
        if (t <= 45)      VM4;   // tile t+1 landed; tile t+2's 4 loads remain
        else if (t == 46) VM0;   // drain: tile 47 landed
        __builtin_amdgcn_s_barrier();
    }

    // epilogue: leaky_relu + head combine + hi/lo split store
    const float w0 = wcomb[0], w1 = wcomb[1], w2 = wcomb[2], w3 = wcomb[3];
    const int q = q0 + wn * 16 + (l & 15);
    #pragma unroll
    for (int m = 0; m < 8; ++m) {
        const int rbase = m0 + wm * 128 + (m >> 2) * 64 + (m & 3) * 16 + (l >> 4) * 4;
        #pragma unroll
        for (int i = 0; i < 4; ++i) {
            float x0 = acc[m][0][i]; x0 = x0 >= 0.f ? x0 : SLOPE * x0;
            float x1 = acc[m][1][i]; x1 = x1 >= 0.f ? x1 : SLOPE * x1;
            float x2 = acc[m][2][i]; x2 = x2 >= 0.f ? x2 : SLOPE * x2;
            float x3 = acc[m][3][i]; x3 = x3 >= 0.f ? x3 : SLOPE * x3;
            const float c = w0 * x0 + w1 * x1 + w2 * x2 + w3 * x3;
            const f16 ch = (f16)c;
            const f16 cl = (f16)(c - (float)ch);
            const size_t off = (size_t)(rbase + i) * QD + q;
            Ch[off] = ch;
            Cl[off] = cl;
        }
    }
}

// ---------------------------------------------------------------------------
// K2: out[t,b,s] = dot(combined[b,s,:], query[t,b,:]) — ring-3, lead-2
//   (R10 version, unchanged). Per batch M=1024 N=512 K=256x3.
//   128x128 tile, BK=32, 24 K-tiles, 4 waves (2M x 2N), 16 MFMA/phase.
// ---------------------------------------------------------------------------
__global__ __launch_bounds__(256) void gemm2_kernel(
    const f16* __restrict__ Ch, const f16* __restrict__ Cl,
    const f16* __restrict__ Qh, const f16* __restrict__ Ql,
    const void* __restrict__ maskp, const float* __restrict__ wcomb,
    const int* __restrict__ flag,
    float* __restrict__ out)
{
    __shared__ f16 lds2[24576];   // 3 slots x (A 4096 + B 4096) f16

    const int tid = threadIdx.x;
    const int l  = tid & 63;
    const int wv = tid >> 6;
    const int wm = wv >> 1;          // s half
    const int wn = wv & 1;           // t half
    const int b  = blockIdx.z;
    const int s0 = blockIdx.x * 128;
    const int t0 = blockIdx.y * 128;

    const int rowc = tid >> 2;
    const int xk   = ((tid & 3) ^ ((rowc >> 1) & 3)) * 8;
    const int stgA = (b * Sn + s0 + rowc) * QD + xk;   // +64*QD instr2
    const int stgB = (b * Tn + t0 + rowc) * QD + xk;   // +64*QD instr2

    const int xf  = ((l >> 1) & 3);
    const int aFrag = (wm * 64 + (l & 15)) * 32 + (((l >> 4) ^ xf) * 8);
    const int bFrag = 4096 + (wn * 64 + (l & 15)) * 32 + (((l >> 4) ^ xf) * 8);

    f32x4 acc[4][4];
    #pragma unroll
    for (int m = 0; m < 4; ++m)
        #pragma unroll
        for (int n = 0; n < 4; ++n) acc[m][n] = (f32x4){0.f, 0.f, 0.f, 0.f};

    auto stage1 = [&](int t) {
        const f16* As = (t < 8) ? Ch : ((t < 16) ? Cl : Ch);
        const f16* Bs = (t < 16) ? Qh : Ql;
        const int kofs = (t & 7) * 32;
        f16* dst = lds2 + (t % 3) * 8192 + wv * 512;
        G2L(As + stgA + kofs,           dst);
        G2L(As + stgA + 64 * QD + kofs, dst + 2048);
        G2L(Bs + stgB + kofs,           dst + 4096);
        G2L(Bs + stgB + 64 * QD + kofs, dst + 4096 + 2048);
    };

    stage1(0);
    stage1(1);
    VM4;
    __builtin_amdgcn_s_barrier();

    #pragma unroll
    for (int kt = 0; kt < 24; ++kt) {
        if (kt + 2 < 24) stage1(kt + 2);
        const f16* Lb = lds2 + (kt % 3) * 8192;
        f16x8 af[4], bfr[4];
        #pragma unroll
        for (int m = 0; m < 4; ++m) af[m] = *(const f16x8*)(Lb + aFrag + m * 512);
        #pragma unroll
        for (int n = 0; n < 4; ++n) bfr[n] = *(const f16x8*)(Lb + bFrag + n * 512);
        __builtin_amdgcn_s_setprio(1);
        #pragma unroll
        for (int m = 0; m < 4; ++m) {
            #pragma unroll
            for (int n = 0; n < 4; ++n)
                acc[m][n] = __builtin_amdgcn_mfma_f32_16x16x32_f16(
                    af[m], bfr[n], acc[m][n], 0, 0, 0);
        }
        __builtin_amdgcn_s_setprio(0);
        if (kt <= 21)      VM4;
        else if (kt == 22) VM0;
        LG0;
        __builtin_amdgcn_s_barrier();
    }

    const float sumw = wcomb[0] + wcomb[1] + wcomb[2] + wcomb[3];
    const float maskval = NEG_INF * sumw;
    const bool is_int = (flag[0] != 0);
    const int rbase = s0 + wm * 64 + (l >> 4) * 4;

    bool msk[4][4];
    #pragma unroll
    for (int m = 0; m < 4; ++m)
        #pragma unroll
        for (int i = 0; i < 4; ++i) {
            const int idx = b * Sn + rbase + m * 16 + i;
            int mm;
            if (is_int) mm = ((const int*)maskp)[idx];
            else        mm = (int)((const unsigned char*)maskp)[idx];
            msk[m][i] = (mm != 0);
        }

    #pragma unroll
    for (int m = 0; m < 4; ++m)
        #pragma unroll
        for (int n = 0; n < 4; ++n) {
            const int t = t0 + wn * 64 + n * 16 + (l & 15);
            float vals[4];
            #pragma unroll
            for (int i = 0; i < 4; ++i)
                vals[i] = msk[m][i] ? maskval : acc[m][n][i];
            *(float4*)(out + ((size_t)t * Bn + b) * Sn + rbase + m * 16)
                = make_float4(vals[0], vals[1], vals[2], vals[3]);
        }
}

// ---------------------------------------------------------------------------
// K3: in-place softmax over last dim (S=1024). One block per (t,b) row.
// ---------------------------------------------------------------------------
__global__ __launch_bounds__(256) void softmax_kernel(float* __restrict__ out) {
    const size_t row = blockIdx.x;
    float* p = out + row * (size_t)Sn;
    const int tid = threadIdx.x;
    const int lane = tid & 63, wave = tid >> 6;

    float4 v = ((const float4*)p)[tid];

    float m = fmaxf(fmaxf(v.x, v.y), fmaxf(v.z, v.w));
    #pragma unroll
    for (int off = 32; off; off >>= 1) m = fmaxf(m, __shfl_down(m, off));
    __shared__ float smax[4];
    __shared__ float sm_all;
    if (lane == 0) smax[wave] = m;
    __syncthreads();
    if (tid == 0) sm_all = fmaxf(fmaxf(smax[0], smax[1]), fmaxf(smax[2], smax[3]));
    __syncthreads();
    m = sm_all;

    float e0 = __expf(v.x - m), e1 = __expf(v.y - m);
    float e2 = __expf(v.z - m), e3 = __expf(v.w - m);
    float s = e0 + e1 + e2 + e3;
    #pragma unroll
    for (int off = 32; off; off >>= 1) s += __shfl_down(s, off);
    __shared__ float ssum[4];
    __shared__ float ss_all;
    if (lane == 0) ssum[wave] = s;
    __syncthreads();
    if (tid == 0) ss_all = ssum[0] + ssum[1] + ssum[2] + ssum[3];
    __syncthreads();
    const float inv = 1.0f / ss_all;

    ((float4*)p)[tid] = make_float4(e0 * inv, e1 * inv, e2 * inv, e3 * inv);
}

// ---------------------------------------------------------------------------
extern "C" void kernel_launch(void* const* d_in, const int* in_sizes, int n_in,
                              void* d_out, int out_size, void* d_ws, size_t ws_size,
                              hipStream_t stream) {
    const float* src   = (const float*)d_in[0];  // (16,1024,512)
    const void*  maskp = d_in[1];                // (16,1024) bool/int32
    const float* query = (const float*)d_in[2];  // (512,16,256)
    const float* Wsrc  = (const float*)d_in[3];  // (512,1024)
    const float* wcomb = (const float*)d_in[4];  // (4,)
    float* out = (float*)d_out;                  // (512,16,1024)

    // workspace layout (total 50 MB + 256 B; Qh/Ql alias Ah/Al after gemm1)
    constexpr size_t MB = 1024 * 1024;
    char* ws = (char*)d_ws;
    int* flag = (int*)ws;
    f16* Ah  = (f16*)(ws + 256);
    f16* Al  = (f16*)(ws + 256 + 16 * MB);
    f16* Bht = (f16*)(ws + 256 + 32 * MB);
    f16* Blt = (f16*)(ws + 256 + 33 * MB);
    f16* Ch  = (f16*)(ws + 256 + 34 * MB);
    f16* Cl  = (f16*)(ws + 256 + 42 * MB);
    f16* Qh  = (f16*)(ws + 256);            // aliases Ah (free after gemm1)
    f16* Ql  = (f16*)(ws + 256 + 4 * MB);   // aliases Ah region

    detect_mask_kernel<<<1, 256, 0, stream>>>((const unsigned char*)maskp, flag);

    conv_a_kernel<<<(Mn * En) / (256 * 4), 256, 0, stream>>>(src, Ah, Al);
    {
        dim3 grid((Hn * QD) / 64, En / 64);  // (16, 8)
        conv_b_kernel<<<grid, 256, 0, stream>>>(Wsrc, Bht, Blt);
    }
    {
        dim3 grid(Mn / 256, QD / 64);        // (64, 4) = 256 blocks, 1/CU
        gemm1_kernel<<<grid, 512, 0, stream>>>(Ah, Al, Bht, Blt, wcomb, Ch, Cl);
    }
    conv_q_kernel<<<(Tn * Bn) / 4, 256, 0, stream>>>(query, Qh, Ql);
    {
        dim3 grid(Sn / 128, Tn / 128, Bn);   // (8, 4, 16) = 512 blocks
        gemm2_kernel<<<grid, 256, 0, stream>>>(Ch, Cl, Qh, Ql, maskp, wcomb, flag, out);
    }
    softmax_kernel<<<Tn * Bn, 256, 0, stream>>>(out);
}

// Round 13
// 119.548 us; speedup vs baseline: 1.2109x; 1.2109x over previous
//
#include <hip/hip_runtime.h>
#include <hip/hip_bf16.h>
#include <cstdint>

// Problem dims (fixed by reference setup_inputs)
constexpr int Bn = 16;    // batch
constexpr int Sn = 1024;  // source length
constexpr int Tn = 512;   // query steps
constexpr int QD = 256;   // query vec size
constexpr int En = 512;   // src encoding size
constexpr int Hn = 4;     // heads
constexpr float SLOPE = 0.01f;   // jax.nn.leaky_relu default
constexpr float NEG_INF = -1e9f;
constexpr int Mn = Bn * Sn;      // 16384 rows of the projection GEMM

typedef _Float16 f16;
typedef f16 f16x4 __attribute__((ext_vector_type(4)));
typedef f16 f16x8 __attribute__((ext_vector_type(8)));
typedef float f32x4 __attribute__((ext_vector_type(4)));

// async global->LDS, 16B per lane; dest = wave-uniform base + lane*16
#define G2L(g, l) __builtin_amdgcn_global_load_lds(                      \
    (const __attribute__((address_space(1))) void*)(g),                  \
    (__attribute__((address_space(3))) void*)(l), 16, 0, 0)

#define VM6 asm volatile("s_waitcnt vmcnt(6)" ::: "memory")
#define VM4 asm volatile("s_waitcnt vmcnt(4)" ::: "memory")
#define VM0 asm volatile("s_waitcnt vmcnt(0)" ::: "memory")
#define LG0 asm volatile("s_waitcnt lgkmcnt(0)" ::: "memory")

// ---------------------------------------------------------------------------
// K0: detect mask dtype (bool bytes vs int32) — writes flag (1 = int32) to ws
// ---------------------------------------------------------------------------
__global__ void detect_mask_kernel(const unsigned char* __restrict__ mask_bytes,
                                   int* __restrict__ flag) {
    __shared__ int cnt;
    if (threadIdx.x == 0) cnt = 0;
    __syncthreads();
    int local = 0;
    for (int p = threadIdx.x; p < 4096; p += 256) {
        if ((p & 3) != 0 && mask_bytes[p] != 0) local++;
    }
    atomicAdd(&cnt, local);
    __syncthreads();
    if (threadIdx.x == 0) flag[0] = (cnt == 0) ? 1 : 0;
}

// ---------------------------------------------------------------------------
// C1: split src (16384x512 f32) into Ah + Al (f16 row-major), exact hi/lo
// ---------------------------------------------------------------------------
__global__ __launch_bounds__(256) void conv_a_kernel(
    const float* __restrict__ src, f16* __restrict__ Ah, f16* __restrict__ Al)
{
    const size_t i4 = (size_t)blockIdx.x * 256 + threadIdx.x;
    const size_t base = i4 * 4;
    const float4 v = *(const float4*)(src + base);
    f16x4 hi, lo;
    const float xs[4] = {v.x, v.y, v.z, v.w};
    #pragma unroll
    for (int j = 0; j < 4; ++j) {
        f16 h = (f16)xs[j];
        hi[j] = h;
        lo[j] = (f16)(xs[j] - (float)h);
    }
    *(f16x4*)(Ah + base) = hi;
    *(f16x4*)(Al + base) = lo;
}

// ---------------------------------------------------------------------------
// C2: W (512x1024 f32) -> Bht, Blt (1024x512 f16) transposed + hi/lo split
// ---------------------------------------------------------------------------
__global__ __launch_bounds__(256) void conv_b_kernel(
    const float* __restrict__ W, f16* __restrict__ Bht, f16* __restrict__ Blt)
{
    __shared__ float T[64][65];
    const int tid = threadIdx.x;
    const int n0 = blockIdx.x * 64;
    const int k0 = blockIdx.y * 64;
    #pragma unroll
    for (int p = 0; p < 4; ++p) {
        const int e = p * 256 + tid;
        const int r = e >> 4;
        const int c4 = e & 15;
        const float4 v = *(const float4*)(W + (size_t)(k0 + r) * (Hn * QD) + n0 + c4 * 4);
        T[r][c4 * 4 + 0] = v.x; T[r][c4 * 4 + 1] = v.y;
        T[r][c4 * 4 + 2] = v.z; T[r][c4 * 4 + 3] = v.w;
    }
    __syncthreads();
    #pragma unroll
    for (int p = 0; p < 4; ++p) {
        const int e = p * 256 + tid;
        const int r = e >> 4;
        const int c4 = e & 15;
        f16x4 hi, lo;
        #pragma unroll
        for (int j = 0; j < 4; ++j) {
            const float x = T[c4 * 4 + j][r];
            f16 h = (f16)x;
            hi[j] = h;
            lo[j] = (f16)(x - (float)h);
        }
        const size_t off = (size_t)(n0 + r) * En + k0 + c4 * 4;
        *(f16x4*)(Bht + off) = hi;
        *(f16x4*)(Blt + off) = lo;
    }
}

// ---------------------------------------------------------------------------
// C3: split query (512,16,256) f32 -> Qh, Ql (b,t,q) f16.
// ---------------------------------------------------------------------------
__global__ __launch_bounds__(256) void conv_q_kernel(
    const float* __restrict__ query, f16* __restrict__ Qh, f16* __restrict__ Ql)
{
    const int tid = threadIdx.x;
    const int rloc = tid >> 6;
    const int lane = tid & 63;
    const int row = blockIdx.x * 4 + rloc;   // (t,b) pair, t-major
    const int t = row >> 4, b = row & 15;
    const float4 v = *(const float4*)(query + (size_t)row * QD + lane * 4);
    f16x4 hi, lo;
    const float xs[4] = {v.x, v.y, v.z, v.w};
    #pragma unroll
    for (int j = 0; j < 4; ++j) {
        f16 h = (f16)xs[j];
        hi[j] = h;
        lo[j] = (f16)(xs[j] - (float)h);
    }
    const size_t off = ((size_t)(b * Tn + t)) * QD + lane * 4;
    *(f16x4*)(Qh + off) = hi;
    *(f16x4*)(Ql + off) = lo;
}

// ---------------------------------------------------------------------------
// K1: 128(rows) x 256(cols = 64q x 4heads) tile, BK=32, ring-3, lead-2.
//   R10 structure verbatim (best known: 60.6 us, MfmaUtil 34%).
//   R13: XCD-aware bijective block swizzle — the 4 blocks sharing an A
//   panel (4 q-tiles of the same m-tile) become consecutive dispatch ids
//   on ONE XCD: swz = (bid%8)*64 + bid/8; m-tile = swz>>2, q-tile = swz&3.
//   A HBM fetch ~4x -> ~1x (rest L2 hits).
// ---------------------------------------------------------------------------
__global__ __launch_bounds__(256) void gemm1_kernel(
    const f16* __restrict__ Ah, const f16* __restrict__ Al,
    const f16* __restrict__ Bht, const f16* __restrict__ Blt,
    const float* __restrict__ wcomb,
    f16* __restrict__ Ch, f16* __restrict__ Cl)
{
    __shared__ f16 lds_f[36864];   // 3 slots x 12288 f16 = 72 KB

    const int tid = threadIdx.x;
    const int l  = tid & 63;
    const int wv = tid >> 6;         // 0..3
    const int wm = wv >> 1;          // M half (64 rows)
    const int wn = wv & 1;           // q half (32 q)

    // XCD swizzle: 512 blocks, 8 XCDs, 64 per XCD; same-A quads co-XCD
    const int bid = blockIdx.x;
    const int swz = (bid & 7) * 64 + (bid >> 3);
    const int m0 = (swz >> 2) * 128;
    const int q0 = (swz & 3) * 64;

    // staging constants: chunk c = i*256 + tid; row/col = c>>2, k4 = c&3
    const int rc  = tid >> 2;                                   // 0..63
    const int xk  = ((tid & 3) ^ ((tid >> 3) & 3)) * 8;         // XOR'd k-chunk
    const int stgA = (m0 + rc) * En + xk;        // A rows rc, rc+64
    const int stgB = (q0 + rc) * En + xk;        // B strips: +i*QD*En per head

    // fragment ds_read bases (f16 idx); xor nibble lane-constant
    const int xf  = (l >> 1) & 3;
    const int kx  = ((l >> 4) ^ xf) * 8;
    const int aFrag = (wm * 64 + (l & 15)) * 32 + kx;            // + m*512
    const int bFrag = 4096 + (wn * 32 + (l & 15)) * 32 + kx;     // + h*2048 + qs*512

    f32x4 acc[4][8];   // [m][f = h*2 + qsub]
    #pragma unroll
    for (int m = 0; m < 4; ++m)
        #pragma unroll
        for (int f = 0; f < 8; ++f) acc[m][f] = (f32x4){0.f, 0.f, 0.f, 0.f};

    auto stage1 = [&](int t) {
        const f16* As = (t < 16) ? Ah : ((t < 32) ? Al : Ah);
        const f16* Bs = (t < 32) ? Bht : Blt;
        const int kofs = (t & 15) * 32;
        f16* dst = lds_f + (t % 3) * 12288 + wv * 512;
        G2L(As + stgA + kofs,                dst);
        G2L(As + stgA + 64 * En + kofs,      dst + 2048);
        G2L(Bs + stgB + kofs,                dst + 4096);
        G2L(Bs + stgB + QD * En + kofs,      dst + 4096 + 2048);
        G2L(Bs + stgB + 2 * QD * En + kofs,  dst + 4096 + 4096);
        G2L(Bs + stgB + 3 * QD * En + kofs,  dst + 4096 + 6144);
    };

    // prologue: tiles 0,1 staged; wait tile0 (6 of tile1 outstanding)
    stage1(0);
    stage1(1);
    VM6;
    __builtin_amdgcn_s_barrier();

    #pragma unroll
    for (int t = 0; t < 48; ++t) {
        if (t + 2 < 48) stage1(t + 2);   // issue next-next tile first
        const f16* Lb = lds_f + (t % 3) * 12288;
        f16x8 af[4], bfr[8];
        #pragma unroll
        for (int m = 0; m < 4; ++m) af[m] = *(const f16x8*)(Lb + aFrag + m * 512);
        #pragma unroll
        for (int f = 0; f < 8; ++f)
            bfr[f] = *(const f16x8*)(Lb + bFrag + (f >> 1) * 2048 + (f & 1) * 512);
        __builtin_amdgcn_s_setprio(1);
        #pragma unroll
        for (int m = 0; m < 4; ++m) {
            #pragma unroll
            for (int f = 0; f < 8; ++f)
                acc[m][f] = __builtin_amdgcn_mfma_f32_16x16x32_f16(
                    af[m], bfr[f], acc[m][f], 0, 0, 0);
        }
        __builtin_amdgcn_s_setprio(0);
        if (t <= 45)      VM6;   // tile t+1 landed (tile t+2's 6 remain)
        else if (t == 46) VM0;   // drain: tile 47 landed
        LG0;                      // trivially satisfied; pins WAR for slot reuse
        __builtin_amdgcn_s_barrier();
    }

    // epilogue: leaky_relu + head combine + hi/lo split store
    const float w0 = wcomb[0], w1 = wcomb[1], w2 = wcomb[2], w3 = wcomb[3];
    const int rbase = m0 + wm * 64 + (l >> 4) * 4;
    #pragma unroll
    for (int m = 0; m < 4; ++m) {
        #pragma unroll
        for (int qs = 0; qs < 2; ++qs) {
            const int q = q0 + wn * 32 + qs * 16 + (l & 15);
            #pragma unroll
            for (int i = 0; i < 4; ++i) {
                float x0 = acc[m][0 + qs][i]; x0 = x0 >= 0.f ? x0 : SLOPE * x0;
                float x1 = acc[m][2 + qs][i]; x1 = x1 >= 0.f ? x1 : SLOPE * x1;
                float x2 = acc[m][4 + qs][i]; x2 = x2 >= 0.f ? x2 : SLOPE * x2;
                float x3 = acc[m][6 + qs][i]; x3 = x3 >= 0.f ? x3 : SLOPE * x3;
                const float c = w0 * x0 + w1 * x1 + w2 * x2 + w3 * x3;
                const f16 ch = (f16)c;
                const f16 cl = (f16)(c - (float)ch);
                const size_t off = (size_t)(rbase + m * 16 + i) * QD + q;
                Ch[off] = ch;
                Cl[off] = cl;
            }
        }
    }
}

// ---------------------------------------------------------------------------
// K2: out[t,b,s] = dot(combined[b,s,:], query[t,b,:]) — ring-3, lead-2
//   (R10 structure verbatim). R13: XCD swizzle groups blocks by batch b —
//   one b's full working set (Ch/Cl 1 MB + Qh/Ql 0.5 MB) is XCD-L2-resident;
//   each XCD serves 2 consecutive b's (3 MB < 4 MB L2).
// ---------------------------------------------------------------------------
__global__ __launch_bounds__(256) void gemm2_kernel(
    const f16* __restrict__ Ch, const f16* __restrict__ Cl,
    const f16* __restrict__ Qh, const f16* __restrict__ Ql,
    const void* __restrict__ maskp, const float* __restrict__ wcomb,
    const int* __restrict__ flag,
    float* __restrict__ out)
{
    __shared__ f16 lds2[24576];   // 3 slots x (A 4096 + B 4096) f16

    const int tid = threadIdx.x;
    const int l  = tid & 63;
    const int wv = tid >> 6;
    const int wm = wv >> 1;          // s half
    const int wn = wv & 1;           // t half

    // XCD swizzle: 512 blocks; swz = [b(16)][s-tile(8)][t-tile(4)]
    const int bid = blockIdx.x;
    const int swz = (bid & 7) * 64 + (bid >> 3);
    const int b   = swz >> 5;
    const int s0  = ((swz >> 2) & 7) * 128;
    const int t0  = (swz & 3) * 128;

    const int rowc = tid >> 2;
    const int xk   = ((tid & 3) ^ ((rowc >> 1) & 3)) * 8;
    const int stgA = (b * Sn + s0 + rowc) * QD + xk;   // +64*QD instr2
    const int stgB = (b * Tn + t0 + rowc) * QD + xk;   // +64*QD instr2

    const int xf  = ((l >> 1) & 3);
    const int aFrag = (wm * 64 + (l & 15)) * 32 + (((l >> 4) ^ xf) * 8);
    const int bFrag = 4096 + (wn * 64 + (l & 15)) * 32 + (((l >> 4) ^ xf) * 8);

    f32x4 acc[4][4];
    #pragma unroll
    for (int m = 0; m < 4; ++m)
        #pragma unroll
        for (int n = 0; n < 4; ++n) acc[m][n] = (f32x4){0.f, 0.f, 0.f, 0.f};

    auto stage1 = [&](int t) {
        const f16* As = (t < 8) ? Ch : ((t < 16) ? Cl : Ch);
        const f16* Bs = (t < 16) ? Qh : Ql;
        const int kofs = (t & 7) * 32;
        f16* dst = lds2 + (t % 3) * 8192 + wv * 512;
        G2L(As + stgA + kofs,           dst);
        G2L(As + stgA + 64 * QD + kofs, dst + 2048);
        G2L(Bs + stgB + kofs,           dst + 4096);
        G2L(Bs + stgB + 64 * QD + kofs, dst + 4096 + 2048);
    };

    stage1(0);
    stage1(1);
    VM4;
    __builtin_amdgcn_s_barrier();

    #pragma unroll
    for (int kt = 0; kt < 24; ++kt) {
        if (kt + 2 < 24) stage1(kt + 2);
        const f16* Lb = lds2 + (kt % 3) * 8192;
        f16x8 af[4], bfr[4];
        #pragma unroll
        for (int m = 0; m < 4; ++m) af[m] = *(const f16x8*)(Lb + aFrag + m * 512);
        #pragma unroll
        for (int n = 0; n < 4; ++n) bfr[n] = *(const f16x8*)(Lb + bFrag + n * 512);
        __builtin_amdgcn_s_setprio(1);
        #pragma unroll
        for (int m = 0; m < 4; ++m) {
            #pragma unroll
            for (int n = 0; n < 4; ++n)
                acc[m][n] = __builtin_amdgcn_mfma_f32_16x16x32_f16(
                    af[m], bfr[n], acc[m][n], 0, 0, 0);
        }
        __builtin_amdgcn_s_setprio(0);
        if (kt <= 21)      VM4;
        else if (kt == 22) VM0;
        LG0;
        __builtin_amdgcn_s_barrier();
    }

    const float sumw = wcomb[0] + wcomb[1] + wcomb[2] + wcomb[3];
    const float maskval = NEG_INF * sumw;
    const bool is_int = (flag[0] != 0);
    const int rbase = s0 + wm * 64 + (l >> 4) * 4;

    bool msk[4][4];
    #pragma unroll
    for (int m = 0; m < 4; ++m)
        #pragma unroll
        for (int i = 0; i < 4; ++i) {
            const int idx = b * Sn + rbase + m * 16 + i;
            int mm;
            if (is_int) mm = ((const int*)maskp)[idx];
            else        mm = (int)((const unsigned char*)maskp)[idx];
            msk[m][i] = (mm != 0);
        }

    #pragma unroll
    for (int m = 0; m < 4; ++m)
        #pragma unroll
        for (int n = 0; n < 4; ++n) {
            const int t = t0 + wn * 64 + n * 16 + (l & 15);
            float vals[4];
            #pragma unroll
            for (int i = 0; i < 4; ++i)
                vals[i] = msk[m][i] ? maskval : acc[m][n][i];
            *(float4*)(out + ((size_t)t * Bn + b) * Sn + rbase + m * 16)
                = make_float4(vals[0], vals[1], vals[2], vals[3]);
        }
}

// ---------------------------------------------------------------------------
// K3: in-place softmax over last dim (S=1024). One block per (t,b) row.
// ---------------------------------------------------------------------------
__global__ __launch_bounds__(256) void softmax_kernel(float* __restrict__ out) {
    const size_t row = blockIdx.x;
    float* p = out + row * (size_t)Sn;
    const int tid = threadIdx.x;
    const int lane = tid & 63, wave = tid >> 6;

    float4 v = ((const float4*)p)[tid];

    float m = fmaxf(fmaxf(v.x, v.y), fmaxf(v.z, v.w));
    #pragma unroll
    for (int off = 32; off; off >>= 1) m = fmaxf(m, __shfl_down(m, off));
    __shared__ float smax[4];
    __shared__ float sm_all;
    if (lane == 0) smax[wave] = m;
    __syncthreads();
    if (tid == 0) sm_all = fmaxf(fmaxf(smax[0], smax[1]), fmaxf(smax[2], smax[3]));
    __syncthreads();
    m = sm_all;

    float e0 = __expf(v.x - m), e1 = __expf(v.y - m);
    float e2 = __expf(v.z - m), e3 = __expf(v.w - m);
    float s = e0 + e1 + e2 + e3;
    #pragma unroll
    for (int off = 32; off; off >>= 1) s += __shfl_down(s, off);
    __shared__ float ssum[4];
    __shared__ float ss_all;
    if (lane == 0) ssum[wave] = s;
    __syncthreads();
    if (tid == 0) ss_all = ssum[0] + ssum[1] + ssum[2] + ssum[3];
    __syncthreads();
    const float inv = 1.0f / ss_all;

    ((float4*)p)[tid] = make_float4(e0 * inv, e1 * inv, e2 * inv, e3 * inv);
}

// ---------------------------------------------------------------------------
extern "C" void kernel_launch(void* const* d_in, const int* in_sizes, int n_in,
                              void* d_out, int out_size, void* d_ws, size_t ws_size,
                              hipStream_t stream) {
    const float* src   = (const float*)d_in[0];  // (16,1024,512)
    const void*  maskp = d_in[1];                // (16,1024) bool/int32
    const float* query = (const float*)d_in[2];  // (512,16,256)
    const float* Wsrc  = (const float*)d_in[3];  // (512,1024)
    const float* wcomb = (const float*)d_in[4];  // (4,)
    float* out = (float*)d_out;                  // (512,16,1024)

    // workspace layout (total 50 MB + 256 B; Qh/Ql alias Ah/Al after gemm1)
    constexpr size_t MB = 1024 * 1024;
    char* ws = (char*)d_ws;
    int* flag = (int*)ws;
    f16* Ah  = (f16*)(ws + 256);
    f16* Al  = (f16*)(ws + 256 + 16 * MB);
    f16* Bht = (f16*)(ws + 256 + 32 * MB);
    f16* Blt = (f16*)(ws + 256 + 33 * MB);
    f16* Ch  = (f16*)(ws + 256 + 34 * MB);
    f16* Cl  = (f16*)(ws + 256 + 42 * MB);
    f16* Qh  = (f16*)(ws + 256);            // aliases Ah (free after gemm1)
    f16* Ql  = (f16*)(ws + 256 + 4 * MB);   // aliases Ah region

    detect_mask_kernel<<<1, 256, 0, stream>>>((const unsigned char*)maskp, flag);

    conv_a_kernel<<<(Mn * En) / (256 * 4), 256, 0, stream>>>(src, Ah, Al);
    {
        dim3 grid((Hn * QD) / 64, En / 64);  // (16, 8)
        conv_b_kernel<<<grid, 256, 0, stream>>>(Wsrc, Bht, Blt);
    }
    {
        gemm1_kernel<<<512, 256, 0, stream>>>(Ah, Al, Bht, Blt, wcomb, Ch, Cl);
    }
    conv_q_kernel<<<(Tn * Bn) / 4, 256, 0, stream>>>(query, Qh, Ql);
    {
        gemm2_kernel<<<512, 256, 0, stream>>>(Ch, Cl, Qh, Ql, maskp, wcomb, flag, out);
    }
    softmax_kernel<<<Tn * Bn, 256, 0, stream>>>(out);
}

// Round 14
// 115.245 us; speedup vs baseline: 1.2561x; 1.0373x over previous
//
#include <hip/hip_runtime.h>
#include <hip/hip_bf16.h>
#include <cstdint>

// Problem dims (fixed by reference setup_inputs)
constexpr int Bn = 16;    // batch
constexpr int Sn = 1024;  // source length
constexpr int Tn = 512;   // query steps
constexpr int QD = 256;   // query vec size
constexpr int En = 512;   // src encoding size
constexpr int Hn = 4;     // heads
constexpr float SLOPE = 0.01f;   // jax.nn.leaky_relu default
constexpr float NEG_INF = -1e9f;
constexpr int Mn = Bn * Sn;      // 16384 rows of the projection GEMM

typedef _Float16 f16;
typedef f16 f16x4 __attribute__((ext_vector_type(4)));
typedef f16 f16x8 __attribute__((ext_vector_type(8)));
typedef float f32x4 __attribute__((ext_vector_type(4)));

// async global->LDS, 16B per lane; dest = wave-uniform base + lane*16
#define G2L(g, l) __builtin_amdgcn_global_load_lds(                      \
    (const __attribute__((address_space(1))) void*)(g),                  \
    (__attribute__((address_space(3))) void*)(l), 16, 0, 0)

#define VM6 asm volatile("s_waitcnt vmcnt(6)" ::: "memory")
#define VM4 asm volatile("s_waitcnt vmcnt(4)" ::: "memory")
#define VM0 asm volatile("s_waitcnt vmcnt(0)" ::: "memory")
#define LG0 asm volatile("s_waitcnt lgkmcnt(0)" ::: "memory")

// ---------------------------------------------------------------------------
// PREP: fused conv_a (blocks 0..8191) + conv_b (8192..8319) + detect (8320).
//   conv_a: split src (16384x512 f32) -> Ah + Al (f16, exact hi/lo).
//   conv_b: W (512x1024) -> Bht, Blt (1024x512 f16) transposed + split.
//   detect: mask dtype probe -> flag (1 = int32).
// ---------------------------------------------------------------------------
__global__ __launch_bounds__(256) void prep_kernel(
    const float* __restrict__ src, const float* __restrict__ W,
    const unsigned char* __restrict__ mask_bytes,
    f16* __restrict__ Ah, f16* __restrict__ Al,
    f16* __restrict__ Bht, f16* __restrict__ Blt,
    int* __restrict__ flag)
{
    __shared__ float T[64][65];
    __shared__ int cnt;
    const int bid = blockIdx.x;
    const int tid = threadIdx.x;

    if (bid < 8192) {
        // ---- conv_a ----
        const size_t i4 = (size_t)bid * 256 + tid;
        const size_t base = i4 * 4;
        const float4 v = *(const float4*)(src + base);
        f16x4 hi, lo;
        const float xs[4] = {v.x, v.y, v.z, v.w};
        #pragma unroll
        for (int j = 0; j < 4; ++j) {
            f16 h = (f16)xs[j];
            hi[j] = h;
            lo[j] = (f16)(xs[j] - (float)h);
        }
        *(f16x4*)(Ah + base) = hi;
        *(f16x4*)(Al + base) = lo;
    } else if (bid < 8320) {
        // ---- conv_b ----
        const int nb = bid - 8192;
        const int n0 = (nb & 15) * 64;
        const int k0 = (nb >> 4) * 64;
        #pragma unroll
        for (int p = 0; p < 4; ++p) {
            const int e = p * 256 + tid;
            const int r = e >> 4;
            const int c4 = e & 15;
            const float4 v = *(const float4*)(W + (size_t)(k0 + r) * (Hn * QD) + n0 + c4 * 4);
            T[r][c4 * 4 + 0] = v.x; T[r][c4 * 4 + 1] = v.y;
            T[r][c4 * 4 + 2] = v.z; T[r][c4 * 4 + 3] = v.w;
        }
        __syncthreads();
        #pragma unroll
        for (int p = 0; p < 4; ++p) {
            const int e = p * 256 + tid;
            const int r = e >> 4;
            const int c4 = e & 15;
            f16x4 hi, lo;
            #pragma unroll
            for (int j = 0; j < 4; ++j) {
                const float x = T[c4 * 4 + j][r];
                f16 h = (f16)x;
                hi[j] = h;
                lo[j] = (f16)(x - (float)h);
            }
            const size_t off = (size_t)(n0 + r) * En + k0 + c4 * 4;
            *(f16x4*)(Bht + off) = hi;
            *(f16x4*)(Blt + off) = lo;
        }
    } else {
        // ---- detect mask dtype ----
        if (tid == 0) cnt = 0;
        __syncthreads();
        int local = 0;
        for (int p = tid; p < 4096; p += 256) {
            if ((p & 3) != 0 && mask_bytes[p] != 0) local++;
        }
        atomicAdd(&cnt, local);
        __syncthreads();
        if (tid == 0) flag[0] = (cnt == 0) ? 1 : 0;
    }
}

// ---------------------------------------------------------------------------
// C3: split query (512,16,256) f32 -> Qh, Ql (b,t,q) f16. Runs after gemm1
//   (outputs alias the Ah/Al workspace region).
// ---------------------------------------------------------------------------
__global__ __launch_bounds__(256) void conv_q_kernel(
    const float* __restrict__ query, f16* __restrict__ Qh, f16* __restrict__ Ql)
{
    const int tid = threadIdx.x;
    const int rloc = tid >> 6;
    const int lane = tid & 63;
    const int row = blockIdx.x * 4 + rloc;   // (t,b) pair, t-major
    const int t = row >> 4, b = row & 15;
    const float4 v = *(const float4*)(query + (size_t)row * QD + lane * 4);
    f16x4 hi, lo;
    const float xs[4] = {v.x, v.y, v.z, v.w};
    #pragma unroll
    for (int j = 0; j < 4; ++j) {
        f16 h = (f16)xs[j];
        hi[j] = h;
        lo[j] = (f16)(xs[j] - (float)h);
    }
    const size_t off = ((size_t)(b * Tn + t)) * QD + lane * 4;
    *(f16x4*)(Qh + off) = hi;
    *(f16x4*)(Ql + off) = lo;
}

// ---------------------------------------------------------------------------
// K1: 128(rows) x 256(cols = 64q x 4heads) tile, BK=32, ring-3, lead-2.
//   R13 version, frozen (59.6 us, MfmaUtil ~34% = m97-class structural
//   ceiling; fetch-bound theory falsified in R13). XCD-aware swizzle:
//   same-A quads co-XCD.
// ---------------------------------------------------------------------------
__global__ __launch_bounds__(256) void gemm1_kernel(
    const f16* __restrict__ Ah, const f16* __restrict__ Al,
    const f16* __restrict__ Bht, const f16* __restrict__ Blt,
    const float* __restrict__ wcomb,
    f16* __restrict__ Ch, f16* __restrict__ Cl)
{
    __shared__ f16 lds_f[36864];   // 3 slots x 12288 f16 = 72 KB

    const int tid = threadIdx.x;
    const int l  = tid & 63;
    const int wv = tid >> 6;         // 0..3
    const int wm = wv >> 1;          // M half (64 rows)
    const int wn = wv & 1;           // q half (32 q)

    // XCD swizzle: 512 blocks, 8 XCDs, 64 per XCD; same-A quads co-XCD
    const int bid = blockIdx.x;
    const int swz = (bid & 7) * 64 + (bid >> 3);
    const int m0 = (swz >> 2) * 128;
    const int q0 = (swz & 3) * 64;

    // staging constants: chunk c = i*256 + tid; row/col = c>>2, k4 = c&3
    const int rc  = tid >> 2;                                   // 0..63
    const int xk  = ((tid & 3) ^ ((tid >> 3) & 3)) * 8;         // XOR'd k-chunk
    const int stgA = (m0 + rc) * En + xk;        // A rows rc, rc+64
    const int stgB = (q0 + rc) * En + xk;        // B strips: +i*QD*En per head

    // fragment ds_read bases (f16 idx); xor nibble lane-constant
    const int xf  = (l >> 1) & 3;
    const int kx  = ((l >> 4) ^ xf) * 8;
    const int aFrag = (wm * 64 + (l & 15)) * 32 + kx;            // + m*512
    const int bFrag = 4096 + (wn * 32 + (l & 15)) * 32 + kx;     // + h*2048 + qs*512

    f32x4 acc[4][8];   // [m][f = h*2 + qsub]
    #pragma unroll
    for (int m = 0; m < 4; ++m)
        #pragma unroll
        for (int f = 0; f < 8; ++f) acc[m][f] = (f32x4){0.f, 0.f, 0.f, 0.f};

    auto stage1 = [&](int t) {
        const f16* As = (t < 16) ? Ah : ((t < 32) ? Al : Ah);
        const f16* Bs = (t < 32) ? Bht : Blt;
        const int kofs = (t & 15) * 32;
        f16* dst = lds_f + (t % 3) * 12288 + wv * 512;
        G2L(As + stgA + kofs,                dst);
        G2L(As + stgA + 64 * En + kofs,      dst + 2048);
        G2L(Bs + stgB + kofs,                dst + 4096);
        G2L(Bs + stgB + QD * En + kofs,      dst + 4096 + 2048);
        G2L(Bs + stgB + 2 * QD * En + kofs,  dst + 4096 + 4096);
        G2L(Bs + stgB + 3 * QD * En + kofs,  dst + 4096 + 6144);
    };

    // prologue: tiles 0,1 staged; wait tile0 (6 of tile1 outstanding)
    stage1(0);
    stage1(1);
    VM6;
    __builtin_amdgcn_s_barrier();

    #pragma unroll
    for (int t = 0; t < 48; ++t) {
        if (t + 2 < 48) stage1(t + 2);   // issue next-next tile first
        const f16* Lb = lds_f + (t % 3) * 12288;
        f16x8 af[4], bfr[8];
        #pragma unroll
        for (int m = 0; m < 4; ++m) af[m] = *(const f16x8*)(Lb + aFrag + m * 512);
        #pragma unroll
        for (int f = 0; f < 8; ++f)
            bfr[f] = *(const f16x8*)(Lb + bFrag + (f >> 1) * 2048 + (f & 1) * 512);
        __builtin_amdgcn_s_setprio(1);
        #pragma unroll
        for (int m = 0; m < 4; ++m) {
            #pragma unroll
            for (int f = 0; f < 8; ++f)
                acc[m][f] = __builtin_amdgcn_mfma_f32_16x16x32_f16(
                    af[m], bfr[f], acc[m][f], 0, 0, 0);
        }
        __builtin_amdgcn_s_setprio(0);
        if (t <= 45)      VM6;   // tile t+1 landed (tile t+2's 6 remain)
        else if (t == 46) VM0;   // drain: tile 47 landed
        LG0;                      // trivially satisfied; pins WAR for slot reuse
        __builtin_amdgcn_s_barrier();
    }

    // epilogue: leaky_relu + head combine + hi/lo split store
    const float w0 = wcomb[0], w1 = wcomb[1], w2 = wcomb[2], w3 = wcomb[3];
    const int rbase = m0 + wm * 64 + (l >> 4) * 4;
    #pragma unroll
    for (int m = 0; m < 4; ++m) {
        #pragma unroll
        for (int qs = 0; qs < 2; ++qs) {
            const int q = q0 + wn * 32 + qs * 16 + (l & 15);
            #pragma unroll
            for (int i = 0; i < 4; ++i) {
                float x0 = acc[m][0 + qs][i]; x0 = x0 >= 0.f ? x0 : SLOPE * x0;
                float x1 = acc[m][2 + qs][i]; x1 = x1 >= 0.f ? x1 : SLOPE * x1;
                float x2 = acc[m][4 + qs][i]; x2 = x2 >= 0.f ? x2 : SLOPE * x2;
                float x3 = acc[m][6 + qs][i]; x3 = x3 >= 0.f ? x3 : SLOPE * x3;
                const float c = w0 * x0 + w1 * x1 + w2 * x2 + w3 * x3;
                const f16 ch = (f16)c;
                const f16 cl = (f16)(c - (float)ch);
                const size_t off = (size_t)(rbase + m * 16 + i) * QD + q;
                Ch[off] = ch;
                Cl[off] = cl;
            }
        }
    }
}

// ---------------------------------------------------------------------------
// K2: out[t,b,s] = dot(combined[b,s,:], query[t,b,:]) — R13 version, frozen.
//   XCD swizzle groups blocks by batch b: b's working set is XCD-L2-resident
//   and b's OUTPUT rows are written on XCD b>>1 (softmax exploits this).
// ---------------------------------------------------------------------------
__global__ __launch_bounds__(256) void gemm2_kernel(
    const f16* __restrict__ Ch, const f16* __restrict__ Cl,
    const f16* __restrict__ Qh, const f16* __restrict__ Ql,
    const void* __restrict__ maskp, const float* __restrict__ wcomb,
    const int* __restrict__ flag,
    float* __restrict__ out)
{
    __shared__ f16 lds2[24576];   // 3 slots x (A 4096 + B 4096) f16

    const int tid = threadIdx.x;
    const int l  = tid & 63;
    const int wv = tid >> 6;
    const int wm = wv >> 1;          // s half
    const int wn = wv & 1;           // t half

    // XCD swizzle: 512 blocks; swz = [b(16)][s-tile(8)][t-tile(4)]
    const int bid = blockIdx.x;
    const int swz = (bid & 7) * 64 + (bid >> 3);
    const int b   = swz >> 5;
    const int s0  = ((swz >> 2) & 7) * 128;
    const int t0  = (swz & 3) * 128;

    const int rowc = tid >> 2;
    const int xk   = ((tid & 3) ^ ((rowc >> 1) & 3)) * 8;
    const int stgA = (b * Sn + s0 + rowc) * QD + xk;   // +64*QD instr2
    const int stgB = (b * Tn + t0 + rowc) * QD + xk;   // +64*QD instr2

    const int xf  = ((l >> 1) & 3);
    const int aFrag = (wm * 64 + (l & 15)) * 32 + (((l >> 4) ^ xf) * 8);
    const int bFrag = 4096 + (wn * 64 + (l & 15)) * 32 + (((l >> 4) ^ xf) * 8);

    f32x4 acc[4][4];
    #pragma unroll
    for (int m = 0; m < 4; ++m)
        #pragma unroll
        for (int n = 0; n < 4; ++n) acc[m][n] = (f32x4){0.f, 0.f, 0.f, 0.f};

    auto stage1 = [&](int t) {
        const f16* As = (t < 8) ? Ch : ((t < 16) ? Cl : Ch);
        const f16* Bs = (t < 16) ? Qh : Ql;
        const int kofs = (t & 7) * 32;
        f16* dst = lds2 + (t % 3) * 8192 + wv * 512;
        G2L(As + stgA + kofs,           dst);
        G2L(As + stgA + 64 * QD + kofs, dst + 2048);
        G2L(Bs + stgB + kofs,           dst + 4096);
        G2L(Bs + stgB + 64 * QD + kofs, dst + 4096 + 2048);
    };

    stage1(0);
    stage1(1);
    VM4;
    __builtin_amdgcn_s_barrier();

    #pragma unroll
    for (int kt = 0; kt < 24; ++kt) {
        if (kt + 2 < 24) stage1(kt + 2);
        const f16* Lb = lds2 + (kt % 3) * 8192;
        f16x8 af[4], bfr[4];
        #pragma unroll
        for (int m = 0; m < 4; ++m) af[m] = *(const f16x8*)(Lb + aFrag + m * 512);
        #pragma unroll
        for (int n = 0; n < 4; ++n) bfr[n] = *(const f16x8*)(Lb + bFrag + n * 512);
        __builtin_amdgcn_s_setprio(1);
        #pragma unroll
        for (int m = 0; m < 4; ++m) {
            #pragma unroll
            for (int n = 0; n < 4; ++n)
                acc[m][n] = __builtin_amdgcn_mfma_f32_16x16x32_f16(
                    af[m], bfr[n], acc[m][n], 0, 0, 0);
        }
        __builtin_amdgcn_s_setprio(0);
        if (kt <= 21)      VM4;
        else if (kt == 22) VM0;
        LG0;
        __builtin_amdgcn_s_barrier();
    }

    const float sumw = wcomb[0] + wcomb[1] + wcomb[2] + wcomb[3];
    const float maskval = NEG_INF * sumw;
    const bool is_int = (flag[0] != 0);
    const int rbase = s0 + wm * 64 + (l >> 4) * 4;

    bool msk[4][4];
    #pragma unroll
    for (int m = 0; m < 4; ++m)
        #pragma unroll
        for (int i = 0; i < 4; ++i) {
            const int idx = b * Sn + rbase + m * 16 + i;
            int mm;
            if (is_int) mm = ((const int*)maskp)[idx];
            else        mm = (int)((const unsigned char*)maskp)[idx];
            msk[m][i] = (mm != 0);
        }

    #pragma unroll
    for (int m = 0; m < 4; ++m)
        #pragma unroll
        for (int n = 0; n < 4; ++n) {
            const int t = t0 + wn * 64 + n * 16 + (l & 15);
            float vals[4];
            #pragma unroll
            for (int i = 0; i < 4; ++i)
                vals[i] = msk[m][i] ? maskval : acc[m][n][i];
            *(float4*)(out + ((size_t)t * Bn + b) * Sn + rbase + m * 16)
                = make_float4(vals[0], vals[1], vals[2], vals[3]);
        }
}

// ---------------------------------------------------------------------------
// K3: in-place softmax over last dim (S=1024). One block per (t,b) row.
//   R14: XCD-affinity swizzle — row (t,b) runs on XCD b>>1, where gemm2
//   wrote b's tiles (dirty L2 lines) -> read hits L2 instead of HBM.
// ---------------------------------------------------------------------------
__global__ __launch_bounds__(256) void softmax_kernel(float* __restrict__ out) {
    const int bid = blockIdx.x;
    const int k = bid & 7;           // XCD (round-robin dispatch)
    const int r = bid >> 3;          // 0..1023
    const int b = (k << 1) | (r & 1);
    const int t = r >> 1;
    const size_t row = (size_t)t * Bn + b;
    float* p = out + row * (size_t)Sn;
    const int tid = threadIdx.x;
    const int lane = tid & 63, wave = tid >> 6;

    float4 v = ((const float4*)p)[tid];

    float m = fmaxf(fmaxf(v.x, v.y), fmaxf(v.z, v.w));
    #pragma unroll
    for (int off = 32; off; off >>= 1) m = fmaxf(m, __shfl_down(m, off));
    __shared__ float smax[4];
    __shared__ float sm_all;
    if (lane == 0) smax[wave] = m;
    __syncthreads();
    if (tid == 0) sm_all = fmaxf(fmaxf(smax[0], smax[1]), fmaxf(smax[2], smax[3]));
    __syncthreads();
    m = sm_all;

    float e0 = __expf(v.x - m), e1 = __expf(v.y - m);
    float e2 = __expf(v.z - m), e3 = __expf(v.w - m);
    float s = e0 + e1 + e2 + e3;
    #pragma unroll
    for (int off = 32; off; off >>= 1) s += __shfl_down(s, off);
    __shared__ float ssum[4];
    __shared__ float ss_all;
    if (lane == 0) ssum[wave] = s;
    __syncthreads();
    if (tid == 0) ss_all = ssum[0] + ssum[1] + ssum[2] + ssum[3];
    __syncthreads();
    const float inv = 1.0f / ss_all;

    ((float4*)p)[tid] = make_float4(e0 * inv, e1 * inv, e2 * inv, e3 * inv);
}

// ---------------------------------------------------------------------------
extern "C" void kernel_launch(void* const* d_in, const int* in_sizes, int n_in,
                              void* d_out, int out_size, void* d_ws, size_t ws_size,
                              hipStream_t stream) {
    const float* src   = (const float*)d_in[0];  // (16,1024,512)
    const void*  maskp = d_in[1];                // (16,1024) bool/int32
    const float* query = (const float*)d_in[2];  // (512,16,256)
    const float* Wsrc  = (const float*)d_in[3];  // (512,1024)
    const float* wcomb = (const float*)d_in[4];  // (4,)
    float* out = (float*)d_out;                  // (512,16,1024)

    // workspace layout (total 50 MB + 256 B; Qh/Ql alias Ah/Al after gemm1)
    constexpr size_t MB = 1024 * 1024;
    char* ws = (char*)d_ws;
    int* flag = (int*)ws;
    f16* Ah  = (f16*)(ws + 256);
    f16* Al  = (f16*)(ws + 256 + 16 * MB);
    f16* Bht = (f16*)(ws + 256 + 32 * MB);
    f16* Blt = (f16*)(ws + 256 + 33 * MB);
    f16* Ch  = (f16*)(ws + 256 + 34 * MB);
    f16* Cl  = (f16*)(ws + 256 + 42 * MB);
    f16* Qh  = (f16*)(ws + 256);            // aliases Ah (free after gemm1)
    f16* Ql  = (f16*)(ws + 256 + 4 * MB);   // aliases Ah region

    prep_kernel<<<8321, 256, 0, stream>>>(
        src, Wsrc, (const unsigned char*)maskp, Ah, Al, Bht, Blt, flag);

    gemm1_kernel<<<512, 256, 0, stream>>>(Ah, Al, Bht, Blt, wcomb, Ch, Cl);

    conv_q_kernel<<<(Tn * Bn) / 4, 256, 0, stream>>>(query, Qh, Ql);

    gemm2_kernel<<<512, 256, 0, stream>>>(Ch, Cl, Qh, Ql, maskp, wcomb, flag, out);

    softmax_kernel<<<Tn * Bn, 256, 0, stream>>>(out);
}